// Round 7
// baseline (102.306 us; speedup 1.0000x reference)
//
#include <hip/hip_runtime.h>
#include <hip/hip_bf16.h>
#include <stdint.h>

// Problem constants (fixed by the reference)
#define P 2048       // D_STATE
#define HN 64        // D_INPUT
#define L 16384      // kernel_size
#define KQ 4         // K split across blocks (k-quarters)
#define NT 8         // tiles per block (32 cols each -> 256 cols/block)
#define KTWV 4       // kt steps per wave (32 kt per quarter / 8 waves)
#define HL (HN * L)  // 1048576 floats per partial

typedef __bf16 bf16_t;
typedef bf16_t bf16x8 __attribute__((ext_vector_type(8)));
typedef float f32x16 __attribute__((ext_vector_type(16)));

__device__ __forceinline__ float2 cmul(float2 a, float2 b) {
    return make_float2(a.x * b.x - a.y * b.y, a.x * b.y + a.y * b.x);
}

__device__ __forceinline__ uint32_t packbf(float2 v) {
    union { __hip_bfloat162 v; uint32_t u; } cv;
    cv.v = __float22bfloat162_rn(make_float2(v.x, v.y));
    return cv.u;
}

// ---------------------------------------------------------------------------
// Prep: (a) W in bf16 32x32-MFMA A-fragment order: granule gid =
// ((kt*2+q)*2+mt)*64+lane holds A[m=mt*32+(lane&31)][k-run], p-run =
// kt*16 + q*8 + (lane>>5)*4, elements (W_re, -W_im) pairs (k=2p, 2p+1).
// (b) Tcol[p*32 + lc] = A_p^lc (float2), lc in [0,32) — block-invariant.
// (c) a32[p] = A_p^32.
// (d) abase[j*P + p] = A_p^(64j), j in [0,256) — binary exponentiation.
__global__ void mv_prep(const float* __restrict__ Win,
                        const float* __restrict__ Ain,
                        uint4* __restrict__ wexp,
                        float2* __restrict__ tcol,
                        float2* __restrict__ a32,
                        float2* __restrict__ abase) {
    int gid = blockIdx.x * 256 + threadIdx.x;   // 32768
    {   // wexp
        int lane = gid & 63;
        int mt = (gid >> 6) & 1;
        int q = (gid >> 7) & 1;
        int kt = gid >> 8;
        int m = mt * 32 + (lane & 31);
        int p0 = kt * 16 + q * 8 + (lane >> 5) * 4;
        const float4* wp = (const float4*)(Win + (size_t)(m * P + p0) * 2);
        float4 f0 = wp[0], f1 = wp[1];
        float re[4] = {f0.x, f0.z, f1.x, f1.z};
        float im[4] = {f0.y, f0.w, f1.y, f1.w};
        uint32_t o[4];
#pragma unroll
        for (int j = 0; j < 4; ++j)
            o[j] = packbf(make_float2(re[j], -im[j]));
        wexp[gid] = make_uint4(o[0], o[1], o[2], o[3]);
    }
    {   // Tcol: thread handles p = gid>>4, lc = 2*(gid&15) and lc+1
        int p = gid >> 4;
        int e = gid & 15;                      // lc/2
        float2 a = *(const float2*)(Ain + 2 * p);
        float2 a2 = cmul(a, a);
        float2 r = make_float2(1.f, 0.f);
        float2 sq = a2;
#pragma unroll
        for (int b = 0; b < 4; ++b) {
            if ((e >> b) & 1) r = cmul(r, sq);
            sq = cmul(sq, sq);
        }
        float2 ro = cmul(r, a);
        tcol[(size_t)p * 32 + 2 * e] = r;       // A^(2e)
        tcol[(size_t)p * 32 + 2 * e + 1] = ro;  // A^(2e+1)
        if (e == 15) a32[p] = cmul(ro, a);      // A^32
    }
    {   // abase: thread handles p = gid&2047, j in [16*(gid>>11), +16)
        int p = gid & 2047;
        int j16 = gid >> 11;                   // 0..15
        float2 a = *(const float2*)(Ain + 2 * p);
        float2 s = cmul(a, a);                 // A^2
#pragma unroll
        for (int i = 0; i < 5; ++i) s = cmul(s, s);   // A^64
        float2 a64v = s;
        float2 t1k = a64v;
#pragma unroll
        for (int i = 0; i < 4; ++i) t1k = cmul(t1k, t1k);  // A^1024
        float2 r = make_float2(1.f, 0.f);
        float2 sq = t1k;
#pragma unroll
        for (int b = 0; b < 4; ++b) {          // r = (A^1024)^j16
            if ((j16 >> b) & 1) r = cmul(r, sq);
            sq = cmul(sq, sq);
        }
        float2* ab = abase + (size_t)(j16 * 16) * P + p;
#pragma unroll
        for (int i = 0; i < 16; ++i) {
            ab[(size_t)i * P] = r;             // A^(64*(j16*16+i))
            r = cmul(r, a64v);
        }
    }
}

// ---------------------------------------------------------------------------
// Main: grid 256 = KQ(4) x 64 col-groups; 512 thr (8 waves). Block
// (kq, cg): kt in [32kq, 32kq+32), cols [256cg, 256cg+256) as 8 tiles
// of 32. Wave w: 4 kt. ALL state in registers: wreg (A-frags, 64 VGPR)
// and cur[32] (the actual B-fragment complex values for this lane's
// column, 64 VGPR), advanced per tile by cur *= A32[p] (A32 slice in
// 4 KB LDS, same-address broadcast reads). K-loop = pure VALU+MFMA:
// zero global loads, zero LDS on the pack->MFMA critical path, no
// barriers outside the epilogue. Partials to ws; mv_reduce sums the 4
// quarters (deterministic, no atomics — atomics measured +9 us in R6).
__global__ void __launch_bounds__(512, 2) mv_main(
    const uint4* __restrict__ wexp,
    const float2* __restrict__ Tcol,
    const float2* __restrict__ A32,
    const float2* __restrict__ Abase,
    float* __restrict__ part) {
    __shared__ __align__(16) float2 A32s[512];           // 4 KB
    __shared__ __align__(16) float Red[8 * 1056];        // 33 KB (padded)

    const int t = threadIdx.x;
    const int kq = blockIdx.x & 3;
    const int cg = blockIdx.x >> 2;        // 0..63
    const int w = t >> 6;
    const int lw = t & 63;
    const int n = lw & 31;                 // column within 32-wide tile
    const int kh = lw >> 5;                // k-half of the fragment

    // ---- stage this quarter's A32 slice to LDS (broadcast-read later) ----
    A32s[t] = A32[kq * 512 + t];

    // ---- burst-load register-resident state ----
    uint4 wreg[KTWV][2][2];                // [kk][mt][q]  A-fragments
    {
#pragma unroll
        for (int kk = 0; kk < KTWV; ++kk) {
            int kt = kq * 32 + w * KTWV + kk;
#pragma unroll
            for (int q = 0; q < 2; ++q)
#pragma unroll
                for (int mt = 0; mt < 2; ++mt)
                    wreg[kk][mt][q] = wexp[(size_t)(((kt * 2 + q) * 2 + mt) * 64 + lw)];
        }
    }

    // cur[i] = B[p_i][col0 + n] = A_p^(256cg) * A_p^n, p-local index
    // pl(i) = (w*4 + (i>>3))*16 + ((i>>2)&1)*8 + kh*4 + (i&3)
    float2 cur[32];
    {
        const float2* ab = Abase + (size_t)(4 * cg) * P + (size_t)kq * 512;
        const float2* tc = Tcol + n;
        float2 abv[32];
#pragma unroll
        for (int i = 0; i < 32; ++i) {
            int pl = (w * 4 + (i >> 3)) * 16 + ((i >> 2) & 1) * 8 + kh * 4 + (i & 3);
            abv[i] = ab[pl];
        }
#pragma unroll
        for (int i = 0; i < 32; ++i) {
            int pl = (w * 4 + (i >> 3)) * 16 + ((i >> 2) & 1) * 8 + kh * 4 + (i & 3);
            cur[i] = cmul(abv[i], tc[(size_t)(kq * 512 + pl) * 32]);
        }
    }
    __syncthreads();                       // A32s visible

    // epilogue index helpers (C/D layout m74: col = lane&31,
    // row = (r&3) + 8*(r>>2) + 4*(lane>>5))
    const int row = t >> 4;                // 0..31
    const int cp = (t & 15) * 2;           // even column within 32
    const int rr = (row & 3) | ((row >> 3) << 2);
    const int lane0 = cp + ((row >> 2) & 1) * 32;

    for (int j = 0; j < NT; ++j) {
        f32x16 acc0, acc1;                 // [mt]
#pragma unroll
        for (int r = 0; r < 16; ++r) { acc0[r] = 0.f; acc1[r] = 0.f; }

#pragma unroll
        for (int kk = 0; kk < KTWV; ++kk) {
#pragma unroll
            for (int q = 0; q < 2; ++q) {
                uint32_t f[4];
#pragma unroll
                for (int jj = 0; jj < 4; ++jj)
                    f[jj] = packbf(cur[kk * 8 + q * 4 + jj]);
                union { uint4 u; bf16x8 v; } F, A0, A1;
                F.u = make_uint4(f[0], f[1], f[2], f[3]);
                A0.u = wreg[kk][0][q];
                A1.u = wreg[kk][1][q];
                acc0 = __builtin_amdgcn_mfma_f32_32x32x16_bf16(A0.v, F.v, acc0, 0, 0, 0);
                acc1 = __builtin_amdgcn_mfma_f32_32x32x16_bf16(A1.v, F.v, acc1, 0, 0, 0);
            }
        }

        // ---- advance B-frags to the next 32-col tile (overlaps epilogue
        // barrier waits; A32s reads are same-address broadcasts) ----
        if (j < NT - 1) {
#pragma unroll
            for (int i = 0; i < 32; ++i) {
                int pl = (w * 4 + (i >> 3)) * 16 + ((i >> 2) & 1) * 8 + kh * 4 + (i & 3);
                cur[i] = cmul(cur[i], A32s[pl]);
            }
        }

        // ---- per-tile 8-way cross-wave K-reduction (R5-proven) ----
#pragma unroll
        for (int mt = 0; mt < 2; ++mt) {
#pragma unroll
            for (int r = 0; r < 16; ++r)
                Red[w * 1056 + r * 66 + lw] = mt ? acc1[r] : acc0[r];
            __syncthreads();
            float sx = 0.f, sy = 0.f;
#pragma unroll
            for (int ww = 0; ww < 8; ++ww) {
                int base = ww * 1056 + rr * 66 + lane0;
                sx += Red[base];
                sy += Red[base + 1];
            }
            *(float2*)(part + (size_t)kq * HL + (size_t)(mt * 32 + row) * L
                       + cg * 256 + j * 32 + cp) = make_float2(sx, sy);
            __syncthreads();
        }
    }
}

// ---------------------------------------------------------------------------
// Reduce: out[i] = sum over 4 k-quarters of partials. 4 MB out, 16 MB in.
__global__ void mv_reduce(const float4* __restrict__ part,
                          float4* __restrict__ out) {
    int i = blockIdx.x * 256 + threadIdx.x;      // 262144 float4
    float4 a = part[i];
    float4 b = part[i + (HL / 4)];
    float4 c = part[i + 2 * (HL / 4)];
    float4 d = part[i + 3 * (HL / 4)];
    out[i] = make_float4(a.x + b.x + c.x + d.x, a.y + b.y + c.y + d.y,
                         a.z + b.z + c.z + d.z, a.w + b.w + c.w + d.w);
}

// ---------------------------------------------------------------------------
extern "C" void kernel_launch(void* const* d_in, const int* in_sizes, int n_in,
                              void* d_out, int out_size, void* d_ws, size_t ws_size,
                              hipStream_t stream) {
    const float* Ain = nullptr;
    const float* Win = nullptr;
    for (int i = 0; i < n_in; ++i) {
        if (in_sizes[i] == 2 * P) Ain = (const float*)d_in[i];
        else if (in_sizes[i] == 2 * HN * P) Win = (const float*)d_in[i];
    }
    if (!Ain) Ain = (const float*)d_in[0];
    if (!Win) Win = (const float*)d_in[1];
    (void)out_size; (void)ws_size;
    uint4* wexp = (uint4*)d_ws;                                  // 512 KB
    float2* tcol = (float2*)((char*)d_ws + 512 * 1024);          // +512 KB
    float2* a32 = (float2*)((char*)d_ws + 1024 * 1024);          // +16 KB
    float2* abase = (float2*)((char*)d_ws + 2 * 1024 * 1024);    // +4 MB
    float* part = (float*)((char*)d_ws + 8 * 1024 * 1024);       // +16 MB
    mv_prep<<<128, 256, 0, stream>>>(Win, Ain, wexp, tcol, a32, abase);
    mv_main<<<256, 512, 0, stream>>>(wexp, tcol, a32, abase, part);
    mv_reduce<<<1024, 256, 0, stream>>>((const float4*)part, (float4*)d_out);
}

// Round 8
// 80.727 us; speedup vs baseline: 1.2673x; 1.2673x over previous
//
#include <hip/hip_runtime.h>
#include <hip/hip_bf16.h>
#include <stdint.h>

// Problem constants (fixed by the reference)
#define P 2048       // D_STATE
#define HN 64        // D_INPUT
#define L 16384      // kernel_size
#define BN 64        // l-columns per block (2 n-subtiles of 32)
#define KTW 16       // kt steps per wave (128 total / 8 waves)

typedef __bf16 bf16_t;
typedef bf16_t bf16x8 __attribute__((ext_vector_type(8)));
typedef float f32x16 __attribute__((ext_vector_type(16)));

__device__ __forceinline__ float2 cmul(float2 a, float2 b) {
    return make_float2(a.x * b.x - a.y * b.y, a.x * b.y + a.y * b.x);
}

__device__ __forceinline__ uint32_t packbf(float2 v) {
    union { __hip_bfloat162 v; uint32_t u; } cv;
    cv.v = __float22bfloat162_rn(make_float2(v.x, v.y));
    return cv.u;
}

// ---------------------------------------------------------------------------
// Prep: (a) W in bf16 32x32-MFMA A-fragment order: granule gid =
// ((kt*2+q)*2+mt)*64+lane holds A[m=mt*32+(lane&31)][k-run], p-run =
// kt*16 + q*8 + (lane>>5)*4, elements (W_re, -W_im) pairs (k=2p, 2p+1).
// (b) Tcol[p*32 + lc] = A_p^lc (float2), lc in [0,32) — block-invariant.
// (c) a32[p] = A_p^32.
// (d) abase[j*P + p] = A_p^(64j), j in [0,256) — binary exponentiation
//     (f32-exact to ~30 ulp; validated in R3/R5/R7 passes).
__global__ void mv_prep(const float* __restrict__ Win,
                        const float* __restrict__ Ain,
                        uint4* __restrict__ wexp,
                        float2* __restrict__ tcol,
                        float2* __restrict__ a32,
                        float2* __restrict__ abase) {
    int gid = blockIdx.x * 256 + threadIdx.x;   // 32768
    {   // wexp
        int lane = gid & 63;
        int mt = (gid >> 6) & 1;
        int q = (gid >> 7) & 1;
        int kt = gid >> 8;
        int m = mt * 32 + (lane & 31);
        int p0 = kt * 16 + q * 8 + (lane >> 5) * 4;
        const float4* wp = (const float4*)(Win + (size_t)(m * P + p0) * 2);
        float4 f0 = wp[0], f1 = wp[1];
        float re[4] = {f0.x, f0.z, f1.x, f1.z};
        float im[4] = {f0.y, f0.w, f1.y, f1.w};
        uint32_t o[4];
#pragma unroll
        for (int j = 0; j < 4; ++j)
            o[j] = packbf(make_float2(re[j], -im[j]));
        wexp[gid] = make_uint4(o[0], o[1], o[2], o[3]);
    }
    {   // Tcol: thread handles p = gid>>4, lc = 2*(gid&15) and lc+1
        int p = gid >> 4;
        int e = gid & 15;                      // lc/2
        float2 a = *(const float2*)(Ain + 2 * p);
        float2 a2 = cmul(a, a);
        float2 r = make_float2(1.f, 0.f);
        float2 sq = a2;
#pragma unroll
        for (int b = 0; b < 4; ++b) {
            if ((e >> b) & 1) r = cmul(r, sq);
            sq = cmul(sq, sq);
        }
        float2 ro = cmul(r, a);
        tcol[(size_t)p * 32 + 2 * e] = r;       // A^(2e)
        tcol[(size_t)p * 32 + 2 * e + 1] = ro;  // A^(2e+1)
        if (e == 15) a32[p] = cmul(ro, a);      // A^32
    }
    {   // abase: thread handles p = gid&2047, j in [16*(gid>>11), +16)
        int p = gid & 2047;
        int j16 = gid >> 11;                   // 0..15
        float2 a = *(const float2*)(Ain + 2 * p);
        float2 s = cmul(a, a);                 // A^2
#pragma unroll
        for (int i = 0; i < 5; ++i) s = cmul(s, s);   // A^64
        float2 a64v = s;
        float2 t1k = a64v;
#pragma unroll
        for (int i = 0; i < 4; ++i) t1k = cmul(t1k, t1k);  // A^1024
        float2 r = make_float2(1.f, 0.f);
        float2 sq = t1k;
#pragma unroll
        for (int b = 0; b < 4; ++b) {          // r = (A^1024)^j16
            if ((j16 >> b) & 1) r = cmul(r, sq);
            sq = cmul(sq, sq);
        }
        float2* ab = abase + (size_t)(j16 * 16) * P + p;
#pragma unroll
        for (int i = 0; i < 16; ++i) {
            ab[(size_t)i * P] = r;             // A^(64*(j16*16+i))
            r = cmul(r, a64v);
        }
    }
}

// ---------------------------------------------------------------------------
// Main (R1-proven structure, 81.1 us total): grid 256 x 512 thr (8 waves).
// Wave w: kt in [16w, 16w+16), both m-tiles AND both n-subtiles (nt).
// B-fragments generated in-register (Base_nt x Tcol); tv and wexp A-frags
// shared across nt. K-loop fully unrolled with ping-pong register sets.
// ONLY change vs R1: Base build from Abase/A32 tables (2 float4 loads +
// 2 cmuls per 4 p's) instead of 8x log/atan2/exp/sincos per thread —
// removes ~1.5-2.5 us of serial prologue at the observed ~650 MHz clock.
struct StepRegs {
    uint4 a[2][2];      // [mt][q] wexp A-fragments
    float2 tv[8];       // Tcol values [q*4+j]
};

__global__ void __launch_bounds__(512, 2) mv_main(
    const uint4* __restrict__ wexp,
    const float2* __restrict__ Tcol,
    const float2* __restrict__ A32,
    const float2* __restrict__ Abase,
    float* __restrict__ out) {
    __shared__ __align__(16) float ldsp[8192];   // 32 KB: Base0|Base1, then Red

    const int t = threadIdx.x;
    const int bn = blockIdx.x;
    const int w = t >> 6;
    const int lw = t & 63;

    float2* Base0 = (float2*)ldsp;       // [P]  A_p^(64*bn)
    float2* Base1 = Base0 + P;           // [P]  A_p^(64*bn+32)

    {   // Base build from tables — no transcendentals on the critical path
        const float4* abp = (const float4*)(Abase + (size_t)bn * P);
        const float4* a3p = (const float4*)A32;
#pragma unroll
        for (int j = 0; j < 2; ++j) {
            int i = t + 512 * j;             // float4 index, covers P/2 = 1024
            float4 ab = abp[i];
            float4 a3 = a3p[i];
            float2 c0 = cmul(make_float2(ab.x, ab.y), make_float2(a3.x, a3.y));
            float2 c1 = cmul(make_float2(ab.z, ab.w), make_float2(a3.z, a3.w));
            ((float4*)Base0)[i] = ab;
            ((float4*)Base1)[i] = make_float4(c0.x, c0.y, c1.x, c1.y);
        }
    }
    __syncthreads();

    const int n = lw & 31;         // column within 32-wide tile
    const int kh = lw >> 5;        // k-half of the fragment
    const int kt0 = w * KTW;
    const float2* tc = Tcol + n;
    const float4* B0f4 = (const float4*)Base0;
    const float4* B1f4 = (const float4*)Base1;

    f32x16 acc[2][2];              // [mt][nt]
#pragma unroll
    for (int mt = 0; mt < 2; ++mt)
#pragma unroll
        for (int nt = 0; nt < 2; ++nt)
#pragma unroll
            for (int r = 0; r < 16; ++r) acc[mt][nt][r] = 0.f;

    StepRegs s0, s1;

    auto load_step = [&](int kt, StepRegs& s) {
#pragma unroll
        for (int q = 0; q < 2; ++q) {
#pragma unroll
            for (int mt = 0; mt < 2; ++mt)
                s.a[mt][q] = wexp[(size_t)(((kt * 2 + q) * 2 + mt) * 64 + lw)];
            int pb = kt * 16 + q * 8 + kh * 4;
#pragma unroll
            for (int j = 0; j < 4; ++j)
                s.tv[q * 4 + j] = tc[(size_t)(pb + j) * 32];
        }
    };

    auto compute_step = [&](int kt, const StepRegs& s) {
#pragma unroll
        for (int q = 0; q < 2; ++q) {
            int bi = kt * 8 + q * 4 + kh * 2;
            float4 c0 = B0f4[bi], c1 = B0f4[bi + 1];
            float4 d0 = B1f4[bi], d1 = B1f4[bi + 1];
            float2 bb[4] = {make_float2(c0.x, c0.y), make_float2(c0.z, c0.w),
                            make_float2(c1.x, c1.y), make_float2(c1.z, c1.w)};
            float2 dd[4] = {make_float2(d0.x, d0.y), make_float2(d0.z, d0.w),
                            make_float2(d1.x, d1.y), make_float2(d1.z, d1.w)};
            uint32_t f0[4], f1[4];
#pragma unroll
            for (int j = 0; j < 4; ++j) {
                float2 tvv = s.tv[q * 4 + j];
                f0[j] = packbf(cmul(bb[j], tvv));
                f1[j] = packbf(cmul(dd[j], tvv));
            }
            union { uint4 u; bf16x8 v; } F0, F1, A0, A1;
            F0.u = make_uint4(f0[0], f0[1], f0[2], f0[3]);
            F1.u = make_uint4(f1[0], f1[1], f1[2], f1[3]);
            A0.u = s.a[0][q];
            A1.u = s.a[1][q];
            acc[0][0] = __builtin_amdgcn_mfma_f32_32x32x16_bf16(A0.v, F0.v, acc[0][0], 0, 0, 0);
            acc[1][0] = __builtin_amdgcn_mfma_f32_32x32x16_bf16(A1.v, F0.v, acc[1][0], 0, 0, 0);
            acc[0][1] = __builtin_amdgcn_mfma_f32_32x32x16_bf16(A0.v, F1.v, acc[0][1], 0, 0, 0);
            acc[1][1] = __builtin_amdgcn_mfma_f32_32x32x16_bf16(A1.v, F1.v, acc[1][1], 0, 0, 0);
        }
    };

    load_step(kt0, s0);
#pragma unroll
    for (int i = 0; i < KTW; i += 2) {
        if (i + 1 < KTW) load_step(kt0 + i + 1, s1);
        compute_step(kt0 + i, s0);
        if (i + 2 < KTW) load_step(kt0 + i + 2, s0);
        if (i + 1 < KTW) compute_step(kt0 + i + 1, s1);
    }

    // ---- cross-wave reduction (LDS reused: Base is dead) ----
    __syncthreads();
    float* Red = ldsp;                 // 8 waves x 1024 floats
    // C/D layout (m74): col = lane&31, row = (r&3) + 8*(r>>2) + 4*(lane>>5)
    const int row = t >> 4;            // 0..31
    const int colb = (t & 15) * 2;     // even column
    const int rr = (row & 3) | ((row >> 3) << 2);
    const int lane0 = colb + ((row >> 2) & 1) * 32;

#pragma unroll
    for (int mt = 0; mt < 2; ++mt)
#pragma unroll
        for (int nt = 0; nt < 2; ++nt) {
#pragma unroll
            for (int r = 0; r < 16; ++r)
                Red[w * 1024 + r * 64 + lw] = acc[mt][nt][r];
            __syncthreads();
            float sx = 0.f, sy = 0.f;
#pragma unroll
            for (int ww = 0; ww < 8; ++ww) {
                sx += Red[ww * 1024 + rr * 64 + lane0];
                sy += Red[ww * 1024 + rr * 64 + lane0 + 1];
            }
            float2 o2 = make_float2(sx, sy);
            *(float2*)(out + (size_t)(mt * 32 + row) * L + (size_t)bn * BN + nt * 32 + colb) = o2;
            __syncthreads();
        }
}

// ---------------------------------------------------------------------------
extern "C" void kernel_launch(void* const* d_in, const int* in_sizes, int n_in,
                              void* d_out, int out_size, void* d_ws, size_t ws_size,
                              hipStream_t stream) {
    const float* Ain = nullptr;
    const float* Win = nullptr;
    for (int i = 0; i < n_in; ++i) {
        if (in_sizes[i] == 2 * P) Ain = (const float*)d_in[i];
        else if (in_sizes[i] == 2 * HN * P) Win = (const float*)d_in[i];
    }
    if (!Ain) Ain = (const float*)d_in[0];
    if (!Win) Win = (const float*)d_in[1];
    (void)out_size; (void)ws_size;
    uint4* wexp = (uint4*)d_ws;                                  // 512 KB
    float2* tcol = (float2*)((char*)d_ws + 512 * 1024);          // +512 KB
    float2* a32 = (float2*)((char*)d_ws + 1024 * 1024);          // +16 KB
    float2* abase = (float2*)((char*)d_ws + 2 * 1024 * 1024);    // +4 MB
    mv_prep<<<128, 256, 0, stream>>>(Win, Ain, wexp, tcol, a32, abase);
    mv_main<<<256, 512, 0, stream>>>(wexp, tcol, a32, abase, (float*)d_out);
}

// Round 9
// 77.506 us; speedup vs baseline: 1.3200x; 1.0416x over previous
//
#include <hip/hip_runtime.h>
#include <hip/hip_bf16.h>
#include <stdint.h>

// Problem constants (fixed by the reference)
#define P 2048       // D_STATE
#define HN 64        // D_INPUT
#define L 16384      // kernel_size
#define BN 64        // l-columns per block (2 n-subtiles of 32)
#define KTW 16       // kt steps per wave (128 total / 8 waves)

typedef __bf16 bf16_t;
typedef bf16_t bf16x8 __attribute__((ext_vector_type(8)));
typedef float f32x16 __attribute__((ext_vector_type(16)));

__device__ __forceinline__ float2 cmul(float2 a, float2 b) {
    return make_float2(a.x * b.x - a.y * b.y, a.x * b.y + a.y * b.x);
}

// Complex multiply in 2 VALU via packed-f32 (VOP3P). Verified correct in R6.
// t = (ax*bx, ay*bx);  r = (-ay*by + t.lo, ax*by + t.hi) = cmul(a,b)
__device__ __forceinline__ float2 cmul_pk(float2 a, float2 b) {
    float2 t, r;
    asm("v_pk_mul_f32 %0, %1, %2 op_sel:[0,0] op_sel_hi:[1,0]"
        : "=v"(t) : "v"(a), "v"(b));
    asm("v_pk_fma_f32 %0, %1, %2, %3 op_sel:[1,1,0] op_sel_hi:[0,1,1] neg_lo:[1,0,0]"
        : "=v"(r) : "v"(a), "v"(b), "v"(t));
    return r;
}

__device__ __forceinline__ uint32_t packbf(float2 v) {
    union { __hip_bfloat162 v; uint32_t u; } cv;
    cv.v = __float22bfloat162_rn(make_float2(v.x, v.y));
    return cv.u;
}

// ---------------------------------------------------------------------------
// Prep: (a) W in bf16 32x32-MFMA A-fragment order: granule gid =
// ((kt*2+q)*2+mt)*64+lane holds A[m=mt*32+(lane&31)][k-run], p-run =
// kt*16 + q*8 + (lane>>5)*4, elements (W_re, -W_im) pairs (k=2p, 2p+1).
// (b) Tcol[p*32 + lc] = A_p^lc (float2), lc in [0,32) — block-invariant.
// (c) a32[p] = A_p^32.
// (d) abase[j*P + p] = A_p^(64j), j in [0,256) — binary exponentiation
//     (f32-exact to ~30 ulp; validated in R3/R5/R7/R8 passes).
__global__ void mv_prep(const float* __restrict__ Win,
                        const float* __restrict__ Ain,
                        uint4* __restrict__ wexp,
                        float2* __restrict__ tcol,
                        float2* __restrict__ a32,
                        float2* __restrict__ abase) {
    int gid = blockIdx.x * 256 + threadIdx.x;   // 32768
    {   // wexp
        int lane = gid & 63;
        int mt = (gid >> 6) & 1;
        int q = (gid >> 7) & 1;
        int kt = gid >> 8;
        int m = mt * 32 + (lane & 31);
        int p0 = kt * 16 + q * 8 + (lane >> 5) * 4;
        const float4* wp = (const float4*)(Win + (size_t)(m * P + p0) * 2);
        float4 f0 = wp[0], f1 = wp[1];
        float re[4] = {f0.x, f0.z, f1.x, f1.z};
        float im[4] = {f0.y, f0.w, f1.y, f1.w};
        uint32_t o[4];
#pragma unroll
        for (int j = 0; j < 4; ++j)
            o[j] = packbf(make_float2(re[j], -im[j]));
        wexp[gid] = make_uint4(o[0], o[1], o[2], o[3]);
    }
    {   // Tcol: thread handles p = gid>>4, lc = 2*(gid&15) and lc+1
        int p = gid >> 4;
        int e = gid & 15;                      // lc/2
        float2 a = *(const float2*)(Ain + 2 * p);
        float2 a2 = cmul(a, a);
        float2 r = make_float2(1.f, 0.f);
        float2 sq = a2;
#pragma unroll
        for (int b = 0; b < 4; ++b) {
            if ((e >> b) & 1) r = cmul(r, sq);
            sq = cmul(sq, sq);
        }
        float2 ro = cmul(r, a);
        tcol[(size_t)p * 32 + 2 * e] = r;       // A^(2e)
        tcol[(size_t)p * 32 + 2 * e + 1] = ro;  // A^(2e+1)
        if (e == 15) a32[p] = cmul(ro, a);      // A^32
    }
    {   // abase: thread handles p = gid&2047, j in [16*(gid>>11), +16)
        int p = gid & 2047;
        int j16 = gid >> 11;                   // 0..15
        float2 a = *(const float2*)(Ain + 2 * p);
        float2 s = cmul(a, a);                 // A^2
#pragma unroll
        for (int i = 0; i < 5; ++i) s = cmul(s, s);   // A^64
        float2 a64v = s;
        float2 t1k = a64v;
#pragma unroll
        for (int i = 0; i < 4; ++i) t1k = cmul(t1k, t1k);  // A^1024
        float2 r = make_float2(1.f, 0.f);
        float2 sq = t1k;
#pragma unroll
        for (int b = 0; b < 4; ++b) {          // r = (A^1024)^j16
            if ((j16 >> b) & 1) r = cmul(r, sq);
            sq = cmul(sq, sq);
        }
        float2* ab = abase + (size_t)(j16 * 16) * P + p;
#pragma unroll
        for (int i = 0; i < 16; ++i) {
            ab[(size_t)i * P] = r;             // A^(64*(j16*16+i))
            r = cmul(r, a64v);
        }
    }
}

// ---------------------------------------------------------------------------
// Main (R8 champion structure): grid 256 x 512 thr (8 waves). Wave w: kt
// in [16w, 16w+16), both m-tiles AND both n-subtiles. B-fragments
// generated in-register (Base_nt x Tcol); ping-pong K-loop. Changes vs
// R8 (both attributable): (1) in-loop cmul via 2-instr packed-f32
// (v_pk_mul + v_pk_fma, R6-verified numerics) — cuts ~32 VALU/kt/wave;
// (2) epilogue merged to 2 rounds (both m-tiles per round, Red = 64 KB)
// — 4 barriers instead of 8.
struct StepRegs {
    uint4 a[2][2];      // [mt][q] wexp A-fragments
    float2 tv[8];       // Tcol values [q*4+j]
};

__global__ void __launch_bounds__(512, 2) mv_main(
    const uint4* __restrict__ wexp,
    const float2* __restrict__ Tcol,
    const float2* __restrict__ A32,
    const float2* __restrict__ Abase,
    float* __restrict__ out) {
    __shared__ __align__(16) float ldsp[16384];  // 64 KB: Base (32K) -> Red (64K)

    const int t = threadIdx.x;
    const int bn = blockIdx.x;
    const int w = t >> 6;
    const int lw = t & 63;

    float2* Base0 = (float2*)ldsp;       // [P]  A_p^(64*bn)
    float2* Base1 = Base0 + P;           // [P]  A_p^(64*bn+32)

    {   // Base build from tables — no transcendentals on the critical path
        const float4* abp = (const float4*)(Abase + (size_t)bn * P);
        const float4* a3p = (const float4*)A32;
#pragma unroll
        for (int j = 0; j < 2; ++j) {
            int i = t + 512 * j;             // float4 index, covers P/2 = 1024
            float4 ab = abp[i];
            float4 a3 = a3p[i];
            float2 c0 = cmul(make_float2(ab.x, ab.y), make_float2(a3.x, a3.y));
            float2 c1 = cmul(make_float2(ab.z, ab.w), make_float2(a3.z, a3.w));
            ((float4*)Base0)[i] = ab;
            ((float4*)Base1)[i] = make_float4(c0.x, c0.y, c1.x, c1.y);
        }
    }
    __syncthreads();

    const int n = lw & 31;         // column within 32-wide tile
    const int kh = lw >> 5;        // k-half of the fragment
    const int kt0 = w * KTW;
    const float2* tc = Tcol + n;
    const float4* B0f4 = (const float4*)Base0;
    const float4* B1f4 = (const float4*)Base1;

    f32x16 acc[2][2];              // [mt][nt]
#pragma unroll
    for (int mt = 0; mt < 2; ++mt)
#pragma unroll
        for (int nt = 0; nt < 2; ++nt)
#pragma unroll
            for (int r = 0; r < 16; ++r) acc[mt][nt][r] = 0.f;

    StepRegs s0, s1;

    auto load_step = [&](int kt, StepRegs& s) {
#pragma unroll
        for (int q = 0; q < 2; ++q) {
#pragma unroll
            for (int mt = 0; mt < 2; ++mt)
                s.a[mt][q] = wexp[(size_t)(((kt * 2 + q) * 2 + mt) * 64 + lw)];
            int pb = kt * 16 + q * 8 + kh * 4;
#pragma unroll
            for (int j = 0; j < 4; ++j)
                s.tv[q * 4 + j] = tc[(size_t)(pb + j) * 32];
        }
    };

    auto compute_step = [&](int kt, const StepRegs& s) {
#pragma unroll
        for (int q = 0; q < 2; ++q) {
            int bi = kt * 8 + q * 4 + kh * 2;
            float4 c0 = B0f4[bi], c1 = B0f4[bi + 1];
            float4 d0 = B1f4[bi], d1 = B1f4[bi + 1];
            float2 bb[4] = {make_float2(c0.x, c0.y), make_float2(c0.z, c0.w),
                            make_float2(c1.x, c1.y), make_float2(c1.z, c1.w)};
            float2 dd[4] = {make_float2(d0.x, d0.y), make_float2(d0.z, d0.w),
                            make_float2(d1.x, d1.y), make_float2(d1.z, d1.w)};
            uint32_t f0[4], f1[4];
#pragma unroll
            for (int j = 0; j < 4; ++j) {
                float2 tvv = s.tv[q * 4 + j];
                f0[j] = packbf(cmul_pk(bb[j], tvv));
                f1[j] = packbf(cmul_pk(dd[j], tvv));
            }
            union { uint4 u; bf16x8 v; } F0, F1, A0, A1;
            F0.u = make_uint4(f0[0], f0[1], f0[2], f0[3]);
            F1.u = make_uint4(f1[0], f1[1], f1[2], f1[3]);
            A0.u = s.a[0][q];
            A1.u = s.a[1][q];
            acc[0][0] = __builtin_amdgcn_mfma_f32_32x32x16_bf16(A0.v, F0.v, acc[0][0], 0, 0, 0);
            acc[1][0] = __builtin_amdgcn_mfma_f32_32x32x16_bf16(A1.v, F0.v, acc[1][0], 0, 0, 0);
            acc[0][1] = __builtin_amdgcn_mfma_f32_32x32x16_bf16(A0.v, F1.v, acc[0][1], 0, 0, 0);
            acc[1][1] = __builtin_amdgcn_mfma_f32_32x32x16_bf16(A1.v, F1.v, acc[1][1], 0, 0, 0);
        }
    };

    load_step(kt0, s0);
#pragma unroll
    for (int i = 0; i < KTW; i += 2) {
        if (i + 1 < KTW) load_step(kt0 + i + 1, s1);
        compute_step(kt0 + i, s0);
        if (i + 2 < KTW) load_step(kt0 + i + 2, s0);
        if (i + 1 < KTW) compute_step(kt0 + i + 1, s1);
    }

    // ---- cross-wave reduction: 2 rounds (nt), both m-tiles per round ----
    __syncthreads();                   // Base dead, reuse as Red
    float* Red = ldsp;                 // 8 waves x 2 mt x 1024 floats = 64 KB
    // C/D layout (m74): col = lane&31, row = (r&3) + 8*(r>>2) + 4*(lane>>5)
#pragma unroll
    for (int nt = 0; nt < 2; ++nt) {
#pragma unroll
        for (int mt = 0; mt < 2; ++mt)
#pragma unroll
            for (int r = 0; r < 16; ++r)
                Red[(w * 2 + mt) * 1024 + r * 64 + lw] = acc[mt][nt][r];
        __syncthreads();
#pragma unroll
        for (int ri = 0; ri < 2; ++ri) {
            int tau = t + ri * 512;            // task id in [0, 1024)
            int mtr = tau >> 9;                // m-tile this task reduces
            int s = tau & 511;
            int row = s >> 4;                  // 0..31
            int colb = (s & 15) * 2;           // even column
            int rr = (row & 3) | ((row >> 3) << 2);
            int lane0 = colb + ((row >> 2) & 1) * 32;
            float sx = 0.f, sy = 0.f;
#pragma unroll
            for (int ww = 0; ww < 8; ++ww) {
                int base = (ww * 2 + mtr) * 1024 + rr * 64 + lane0;
                sx += Red[base];
                sy += Red[base + 1];
            }
            *(float2*)(out + (size_t)(mtr * 32 + row) * L + (size_t)bn * BN
                       + nt * 32 + colb) = make_float2(sx, sy);
        }
        __syncthreads();
    }
}

// ---------------------------------------------------------------------------
extern "C" void kernel_launch(void* const* d_in, const int* in_sizes, int n_in,
                              void* d_out, int out_size, void* d_ws, size_t ws_size,
                              hipStream_t stream) {
    const float* Ain = nullptr;
    const float* Win = nullptr;
    for (int i = 0; i < n_in; ++i) {
        if (in_sizes[i] == 2 * P) Ain = (const float*)d_in[i];
        else if (in_sizes[i] == 2 * HN * P) Win = (const float*)d_in[i];
    }
    if (!Ain) Ain = (const float*)d_in[0];
    if (!Win) Win = (const float*)d_in[1];
    (void)out_size; (void)ws_size;
    uint4* wexp = (uint4*)d_ws;                                  // 512 KB
    float2* tcol = (float2*)((char*)d_ws + 512 * 1024);          // +512 KB
    float2* a32 = (float2*)((char*)d_ws + 1024 * 1024);          // +16 KB
    float2* abase = (float2*)((char*)d_ws + 2 * 1024 * 1024);    // +4 MB
    mv_prep<<<128, 256, 0, stream>>>(Win, Ain, wexp, tcol, a32, abase);
    mv_main<<<256, 512, 0, stream>>>(wexp, tcol, a32, abase, (float*)d_out);
}

// Round 10
// 76.918 us; speedup vs baseline: 1.3301x; 1.0076x over previous
//
#include <hip/hip_runtime.h>
#include <hip/hip_bf16.h>
#include <stdint.h>

// Problem constants (fixed by the reference)
#define P 2048       // D_STATE
#define HN 64        // D_INPUT
#define L 16384      // kernel_size
#define BN 64        // l-columns per block (2 n-subtiles of 32)
#define KTW 16       // kt steps per wave (128 total / 8 waves)

typedef __bf16 bf16_t;
typedef bf16_t bf16x8 __attribute__((ext_vector_type(8)));
typedef float f32x16 __attribute__((ext_vector_type(16)));

__device__ __forceinline__ float2 cmul(float2 a, float2 b) {
    return make_float2(a.x * b.x - a.y * b.y, a.x * b.y + a.y * b.x);
}

// Complex multiply in 2 VALU via packed-f32 (VOP3P). Verified correct R6/R9.
// t = (ax*bx, ay*bx);  r = (-ay*by + t.lo, ax*by + t.hi) = cmul(a,b)
__device__ __forceinline__ float2 cmul_pk(float2 a, float2 b) {
    float2 t, r;
    asm("v_pk_mul_f32 %0, %1, %2 op_sel:[0,0] op_sel_hi:[1,0]"
        : "=v"(t) : "v"(a), "v"(b));
    asm("v_pk_fma_f32 %0, %1, %2, %3 op_sel:[1,1,0] op_sel_hi:[0,1,1] neg_lo:[1,0,0]"
        : "=v"(r) : "v"(a), "v"(b), "v"(t));
    return r;
}

__device__ __forceinline__ uint32_t packbf(float2 v) {
    union { __hip_bfloat162 v; uint32_t u; } cv;
    cv.v = __float22bfloat162_rn(make_float2(v.x, v.y));
    return cv.u;
}

// ---------------------------------------------------------------------------
// Prep: (a) W in bf16 32x32-MFMA A-fragment order: granule gid =
// ((kt*2+q)*2+mt)*64+lane holds A[m=mt*32+(lane&31)][k-run], p-run =
// kt*16 + q*8 + (lane>>5)*4, elements (W_re, -W_im) pairs (k=2p, 2p+1).
// (b) Tcol[p*32 + lc] = A_p^lc (float2), lc in [0,32) — block-invariant.
// (c) a32[p] = A_p^32.
// (d) abase[j*P + p] = A_p^(64j), j in [0,256) — binary exponentiation
//     (f32-exact to ~30 ulp; validated in R3/R5/R7/R8/R9 passes).
__global__ void mv_prep(const float* __restrict__ Win,
                        const float* __restrict__ Ain,
                        uint4* __restrict__ wexp,
                        float2* __restrict__ tcol,
                        float2* __restrict__ a32,
                        float2* __restrict__ abase) {
    int gid = blockIdx.x * 256 + threadIdx.x;   // 32768
    {   // wexp
        int lane = gid & 63;
        int mt = (gid >> 6) & 1;
        int q = (gid >> 7) & 1;
        int kt = gid >> 8;
        int m = mt * 32 + (lane & 31);
        int p0 = kt * 16 + q * 8 + (lane >> 5) * 4;
        const float4* wp = (const float4*)(Win + (size_t)(m * P + p0) * 2);
        float4 f0 = wp[0], f1 = wp[1];
        float re[4] = {f0.x, f0.z, f1.x, f1.z};
        float im[4] = {f0.y, f0.w, f1.y, f1.w};
        uint32_t o[4];
#pragma unroll
        for (int j = 0; j < 4; ++j)
            o[j] = packbf(make_float2(re[j], -im[j]));
        wexp[gid] = make_uint4(o[0], o[1], o[2], o[3]);
    }
    {   // Tcol: thread handles p = gid>>4, lc = 2*(gid&15) and lc+1
        int p = gid >> 4;
        int e = gid & 15;                      // lc/2
        float2 a = *(const float2*)(Ain + 2 * p);
        float2 a2 = cmul(a, a);
        float2 r = make_float2(1.f, 0.f);
        float2 sq = a2;
#pragma unroll
        for (int b = 0; b < 4; ++b) {
            if ((e >> b) & 1) r = cmul(r, sq);
            sq = cmul(sq, sq);
        }
        float2 ro = cmul(r, a);
        tcol[(size_t)p * 32 + 2 * e] = r;       // A^(2e)
        tcol[(size_t)p * 32 + 2 * e + 1] = ro;  // A^(2e+1)
        if (e == 15) a32[p] = cmul(ro, a);      // A^32
    }
    {   // abase: thread handles p = gid&2047, j in [16*(gid>>11), +16)
        int p = gid & 2047;
        int j16 = gid >> 11;                   // 0..15
        float2 a = *(const float2*)(Ain + 2 * p);
        float2 s = cmul(a, a);                 // A^2
#pragma unroll
        for (int i = 0; i < 5; ++i) s = cmul(s, s);   // A^64
        float2 a64v = s;
        float2 t1k = a64v;
#pragma unroll
        for (int i = 0; i < 4; ++i) t1k = cmul(t1k, t1k);  // A^1024
        float2 r = make_float2(1.f, 0.f);
        float2 sq = t1k;
#pragma unroll
        for (int b = 0; b < 4; ++b) {          // r = (A^1024)^j16
            if ((j16 >> b) & 1) r = cmul(r, sq);
            sq = cmul(sq, sq);
        }
        float2* ab = abase + (size_t)(j16 * 16) * P + p;
#pragma unroll
        for (int i = 0; i < 16; ++i) {
            ab[(size_t)i * P] = r;             // A^(64*(j16*16+i))
            r = cmul(r, a64v);
        }
    }
}

// ---------------------------------------------------------------------------
// Main (R9 champion + Base-prefetch): grid 256 x 512 thr (8 waves).
// Wave w: kt in [16w, 16w+16), both m-tiles AND both n-subtiles.
// ONLY change vs R9: the 8 Base ds_read_b128 per kt move from
// compute_step into the ping-pong StepRegs (load_step), so each step's
// LDS reads are issued a full compute-step (~300 cyc) before their use
// and compute_step is pure VALU+MFMA. StepRegs 32->64 VGPR; total ~220
// < 256 cap at launch_bounds(512,2) — no spill, no 128-cap trap.
struct StepRegs {
    uint4 a[2][2];      // [mt][q] wexp A-fragments
    float2 tv[8];       // Tcol values [q*4+j]
    float4 cb[4];       // Base0 quads [q*2+half]
    float4 db[4];       // Base1 quads [q*2+half]
};

__global__ void __launch_bounds__(512, 2) mv_main(
    const uint4* __restrict__ wexp,
    const float2* __restrict__ Tcol,
    const float2* __restrict__ A32,
    const float2* __restrict__ Abase,
    float* __restrict__ out) {
    __shared__ __align__(16) float ldsp[16384];  // 64 KB: Base (32K) -> Red (64K)

    const int t = threadIdx.x;
    const int bn = blockIdx.x;
    const int w = t >> 6;
    const int lw = t & 63;

    float2* Base0 = (float2*)ldsp;       // [P]  A_p^(64*bn)
    float2* Base1 = Base0 + P;           // [P]  A_p^(64*bn+32)

    {   // Base build from tables — no transcendentals on the critical path
        const float4* abp = (const float4*)(Abase + (size_t)bn * P);
        const float4* a3p = (const float4*)A32;
#pragma unroll
        for (int j = 0; j < 2; ++j) {
            int i = t + 512 * j;             // float4 index, covers P/2 = 1024
            float4 ab = abp[i];
            float4 a3 = a3p[i];
            float2 c0 = cmul(make_float2(ab.x, ab.y), make_float2(a3.x, a3.y));
            float2 c1 = cmul(make_float2(ab.z, ab.w), make_float2(a3.z, a3.w));
            ((float4*)Base0)[i] = ab;
            ((float4*)Base1)[i] = make_float4(c0.x, c0.y, c1.x, c1.y);
        }
    }
    __syncthreads();

    const int n = lw & 31;         // column within 32-wide tile
    const int kh = lw >> 5;        // k-half of the fragment
    const int kt0 = w * KTW;
    const float2* tc = Tcol + n;
    const float4* B0f4 = (const float4*)Base0;
    const float4* B1f4 = (const float4*)Base1;

    f32x16 acc[2][2];              // [mt][nt]
#pragma unroll
    for (int mt = 0; mt < 2; ++mt)
#pragma unroll
        for (int nt = 0; nt < 2; ++nt)
#pragma unroll
            for (int r = 0; r < 16; ++r) acc[mt][nt][r] = 0.f;

    StepRegs s0, s1;

    auto load_step = [&](int kt, StepRegs& s) {
#pragma unroll
        for (int q = 0; q < 2; ++q) {
#pragma unroll
            for (int mt = 0; mt < 2; ++mt)
                s.a[mt][q] = wexp[(size_t)(((kt * 2 + q) * 2 + mt) * 64 + lw)];
            int pb = kt * 16 + q * 8 + kh * 4;
#pragma unroll
            for (int j = 0; j < 4; ++j)
                s.tv[q * 4 + j] = tc[(size_t)(pb + j) * 32];
            int bi = kt * 8 + q * 4 + kh * 2;
            s.cb[q * 2 + 0] = B0f4[bi];
            s.cb[q * 2 + 1] = B0f4[bi + 1];
            s.db[q * 2 + 0] = B1f4[bi];
            s.db[q * 2 + 1] = B1f4[bi + 1];
        }
    };

    auto compute_step = [&](const StepRegs& s) {
#pragma unroll
        for (int q = 0; q < 2; ++q) {
            float4 c0 = s.cb[q * 2 + 0], c1 = s.cb[q * 2 + 1];
            float4 d0 = s.db[q * 2 + 0], d1 = s.db[q * 2 + 1];
            float2 bb[4] = {make_float2(c0.x, c0.y), make_float2(c0.z, c0.w),
                            make_float2(c1.x, c1.y), make_float2(c1.z, c1.w)};
            float2 dd[4] = {make_float2(d0.x, d0.y), make_float2(d0.z, d0.w),
                            make_float2(d1.x, d1.y), make_float2(d1.z, d1.w)};
            uint32_t f0[4], f1[4];
#pragma unroll
            for (int j = 0; j < 4; ++j) {
                float2 tvv = s.tv[q * 4 + j];
                f0[j] = packbf(cmul_pk(bb[j], tvv));
                f1[j] = packbf(cmul_pk(dd[j], tvv));
            }
            union { uint4 u; bf16x8 v; } F0, F1, A0, A1;
            F0.u = make_uint4(f0[0], f0[1], f0[2], f0[3]);
            F1.u = make_uint4(f1[0], f1[1], f1[2], f1[3]);
            A0.u = s.a[0][q];
            A1.u = s.a[1][q];
            acc[0][0] = __builtin_amdgcn_mfma_f32_32x32x16_bf16(A0.v, F0.v, acc[0][0], 0, 0, 0);
            acc[1][0] = __builtin_amdgcn_mfma_f32_32x32x16_bf16(A1.v, F0.v, acc[1][0], 0, 0, 0);
            acc[0][1] = __builtin_amdgcn_mfma_f32_32x32x16_bf16(A0.v, F1.v, acc[0][1], 0, 0, 0);
            acc[1][1] = __builtin_amdgcn_mfma_f32_32x32x16_bf16(A1.v, F1.v, acc[1][1], 0, 0, 0);
        }
    };

    load_step(kt0, s0);
#pragma unroll
    for (int i = 0; i < KTW; i += 2) {
        if (i + 1 < KTW) load_step(kt0 + i + 1, s1);
        compute_step(s0);
        if (i + 2 < KTW) load_step(kt0 + i + 2, s0);
        if (i + 1 < KTW) compute_step(s1);
    }

    // ---- cross-wave reduction: 2 rounds (nt), both m-tiles per round ----
    __syncthreads();                   // Base dead, reuse as Red
    float* Red = ldsp;                 // 8 waves x 2 mt x 1024 floats = 64 KB
    // C/D layout (m74): col = lane&31, row = (r&3) + 8*(r>>2) + 4*(lane>>5)
#pragma unroll
    for (int nt = 0; nt < 2; ++nt) {
#pragma unroll
        for (int mt = 0; mt < 2; ++mt)
#pragma unroll
            for (int r = 0; r < 16; ++r)
                Red[(w * 2 + mt) * 1024 + r * 64 + lw] = acc[mt][nt][r];
        __syncthreads();
#pragma unroll
        for (int ri = 0; ri < 2; ++ri) {
            int tau = t + ri * 512;            // task id in [0, 1024)
            int mtr = tau >> 9;                // m-tile this task reduces
            int s = tau & 511;
            int row = s >> 4;                  // 0..31
            int colb = (s & 15) * 2;           // even column
            int rr = (row & 3) | ((row >> 3) << 2);
            int lane0 = colb + ((row >> 2) & 1) * 32;
            float sx = 0.f, sy = 0.f;
#pragma unroll
            for (int ww = 0; ww < 8; ++ww) {
                int base = (ww * 2 + mtr) * 1024 + rr * 64 + lane0;
                sx += Red[base];
                sy += Red[base + 1];
            }
            *(float2*)(out + (size_t)(mtr * 32 + row) * L + (size_t)bn * BN
                       + nt * 32 + colb) = make_float2(sx, sy);
        }
        __syncthreads();
    }
}

// ---------------------------------------------------------------------------
extern "C" void kernel_launch(void* const* d_in, const int* in_sizes, int n_in,
                              void* d_out, int out_size, void* d_ws, size_t ws_size,
                              hipStream_t stream) {
    const float* Ain = nullptr;
    const float* Win = nullptr;
    for (int i = 0; i < n_in; ++i) {
        if (in_sizes[i] == 2 * P) Ain = (const float*)d_in[i];
        else if (in_sizes[i] == 2 * HN * P) Win = (const float*)d_in[i];
    }
    if (!Ain) Ain = (const float*)d_in[0];
    if (!Win) Win = (const float*)d_in[1];
    (void)out_size; (void)ws_size;
    uint4* wexp = (uint4*)d_ws;                                  // 512 KB
    float2* tcol = (float2*)((char*)d_ws + 512 * 1024);          // +512 KB
    float2* a32 = (float2*)((char*)d_ws + 1024 * 1024);          // +16 KB
    float2* abase = (float2*)((char*)d_ws + 2 * 1024 * 1024);    // +4 MB
    mv_prep<<<128, 256, 0, stream>>>(Win, Ain, wexp, tcol, a32, abase);
    mv_main<<<256, 512, 0, stream>>>(wexp, tcol, a32, abase, (float*)d_out);
}

// Round 11
// 76.846 us; speedup vs baseline: 1.3313x; 1.0009x over previous
//
#include <hip/hip_runtime.h>
#include <hip/hip_bf16.h>
#include <stdint.h>

// Problem constants (fixed by the reference)
#define P 2048       // D_STATE
#define HN 64        // D_INPUT
#define L 16384      // kernel_size
#define BN 64        // l-columns per block (2 n-subtiles of 32)
#define KTW 16       // kt steps per wave (128 total / 8 waves)

typedef __bf16 bf16_t;
typedef bf16_t bf16x8 __attribute__((ext_vector_type(8)));
typedef float f32x16 __attribute__((ext_vector_type(16)));

__device__ __forceinline__ float2 cmul(float2 a, float2 b) {
    return make_float2(a.x * b.x - a.y * b.y, a.x * b.y + a.y * b.x);
}

// Complex multiply in 2 VALU via packed-f32 (VOP3P). Verified correct R6/R9.
// t = (ax*bx, ay*bx);  r = (-ay*by + t.lo, ax*by + t.hi) = cmul(a,b)
__device__ __forceinline__ float2 cmul_pk(float2 a, float2 b) {
    float2 t, r;
    asm("v_pk_mul_f32 %0, %1, %2 op_sel:[0,0] op_sel_hi:[1,0]"
        : "=v"(t) : "v"(a), "v"(b));
    asm("v_pk_fma_f32 %0, %1, %2, %3 op_sel:[1,1,0] op_sel_hi:[0,1,1] neg_lo:[1,0,0]"
        : "=v"(r) : "v"(a), "v"(b), "v"(t));
    return r;
}

__device__ __forceinline__ uint32_t packbf(float2 v) {
    union { __hip_bfloat162 v; uint32_t u; } cv;
    cv.v = __float22bfloat162_rn(make_float2(v.x, v.y));
    return cv.u;
}

// ---------------------------------------------------------------------------
// Prep: (a) W in bf16 32x32-MFMA A-fragment order: granule gid =
// ((kt*2+q)*2+mt)*64+lane holds A[m=mt*32+(lane&31)][k-run], p-run =
// kt*16 + q*8 + (lane>>5)*4, elements (W_re, -W_im) pairs (k=2p, 2p+1).
// (b) Tcol[p*32 + lc] = A_p^lc (float2), lc in [0,32) — block-invariant.
// (c) a32[p] = A_p^32.
// (d) abase[j*P + p] = A_p^(64j), j in [0,256) — binary exponentiation
//     (f32-exact to ~30 ulp; validated in R3/R5/R7/R8/R9/R10 passes).
__global__ void mv_prep(const float* __restrict__ Win,
                        const float* __restrict__ Ain,
                        uint4* __restrict__ wexp,
                        float2* __restrict__ tcol,
                        float2* __restrict__ a32,
                        float2* __restrict__ abase) {
    int gid = blockIdx.x * 256 + threadIdx.x;   // 32768
    {   // wexp
        int lane = gid & 63;
        int mt = (gid >> 6) & 1;
        int q = (gid >> 7) & 1;
        int kt = gid >> 8;
        int m = mt * 32 + (lane & 31);
        int p0 = kt * 16 + q * 8 + (lane >> 5) * 4;
        const float4* wp = (const float4*)(Win + (size_t)(m * P + p0) * 2);
        float4 f0 = wp[0], f1 = wp[1];
        float re[4] = {f0.x, f0.z, f1.x, f1.z};
        float im[4] = {f0.y, f0.w, f1.y, f1.w};
        uint32_t o[4];
#pragma unroll
        for (int j = 0; j < 4; ++j)
            o[j] = packbf(make_float2(re[j], -im[j]));
        wexp[gid] = make_uint4(o[0], o[1], o[2], o[3]);
    }
    {   // Tcol: thread handles p = gid>>4, lc = 2*(gid&15) and lc+1
        int p = gid >> 4;
        int e = gid & 15;                      // lc/2
        float2 a = *(const float2*)(Ain + 2 * p);
        float2 a2 = cmul(a, a);
        float2 r = make_float2(1.f, 0.f);
        float2 sq = a2;
#pragma unroll
        for (int b = 0; b < 4; ++b) {
            if ((e >> b) & 1) r = cmul(r, sq);
            sq = cmul(sq, sq);
        }
        float2 ro = cmul(r, a);
        tcol[(size_t)p * 32 + 2 * e] = r;       // A^(2e)
        tcol[(size_t)p * 32 + 2 * e + 1] = ro;  // A^(2e+1)
        if (e == 15) a32[p] = cmul(ro, a);      // A^32
    }
    {   // abase: thread handles p = gid&2047, j in [16*(gid>>11), +16)
        int p = gid & 2047;
        int j16 = gid >> 11;                   // 0..15
        float2 a = *(const float2*)(Ain + 2 * p);
        float2 s = cmul(a, a);                 // A^2
#pragma unroll
        for (int i = 0; i < 5; ++i) s = cmul(s, s);   // A^64
        float2 a64v = s;
        float2 t1k = a64v;
#pragma unroll
        for (int i = 0; i < 4; ++i) t1k = cmul(t1k, t1k);  // A^1024
        float2 r = make_float2(1.f, 0.f);
        float2 sq = t1k;
#pragma unroll
        for (int b = 0; b < 4; ++b) {          // r = (A^1024)^j16
            if ((j16 >> b) & 1) r = cmul(r, sq);
            sq = cmul(sq, sq);
        }
        float2* ab = abase + (size_t)(j16 * 16) * P + p;
#pragma unroll
        for (int i = 0; i < 16; ++i) {
            ab[(size_t)i * P] = r;             // A^(64*(j16*16+i))
            r = cmul(r, a64v);
        }
    }
}

// ---------------------------------------------------------------------------
// Main (R9/R10 champion + 3-deep GLOBAL prefetch): grid 256 x 512 thr
// (8 waves). Wave w: kt in [16w, 16w+16), both m-tiles and n-subtiles.
// Change vs R10: global loads (wexp A-frags + Tcol) now use a 3-slot
// rotating prefetch — issue distance ~2 compute-steps (~400+ wall-cyc at
// 2 waves/SIMD) >> L2-hit latency (~200-225 cyc), vs the 1-deep ping-
// pong's marginal ~200-250. Base LDS reads return to compute_step (R9
// style; measured equivalent, saves 64 VGPR). Working set ~215 VGPR
// < 256 cap at launch_bounds(512,2) — no spill.
struct GlobRegs {
    uint4 a[2][2];      // [mt][q] wexp A-fragments (16 VGPR)
    float2 tv[8];       // Tcol values [q*4+j]      (16 VGPR)
};

__global__ void __launch_bounds__(512, 2) mv_main(
    const uint4* __restrict__ wexp,
    const float2* __restrict__ Tcol,
    const float2* __restrict__ A32,
    const float2* __restrict__ Abase,
    float* __restrict__ out) {
    __shared__ __align__(16) float ldsp[16384];  // 64 KB: Base (32K) -> Red (64K)

    const int t = threadIdx.x;
    const int bn = blockIdx.x;
    const int w = t >> 6;
    const int lw = t & 63;

    float2* Base0 = (float2*)ldsp;       // [P]  A_p^(64*bn)
    float2* Base1 = Base0 + P;           // [P]  A_p^(64*bn+32)

    {   // Base build from tables — no transcendentals on the critical path
        const float4* abp = (const float4*)(Abase + (size_t)bn * P);
        const float4* a3p = (const float4*)A32;
#pragma unroll
        for (int j = 0; j < 2; ++j) {
            int i = t + 512 * j;             // float4 index, covers P/2 = 1024
            float4 ab = abp[i];
            float4 a3 = a3p[i];
            float2 c0 = cmul(make_float2(ab.x, ab.y), make_float2(a3.x, a3.y));
            float2 c1 = cmul(make_float2(ab.z, ab.w), make_float2(a3.z, a3.w));
            ((float4*)Base0)[i] = ab;
            ((float4*)Base1)[i] = make_float4(c0.x, c0.y, c1.x, c1.y);
        }
    }
    __syncthreads();

    const int n = lw & 31;         // column within 32-wide tile
    const int kh = lw >> 5;        // k-half of the fragment
    const int kt0 = w * KTW;
    const float2* tc = Tcol + n;
    const float4* B0f4 = (const float4*)Base0;
    const float4* B1f4 = (const float4*)Base1;

    f32x16 acc[2][2];              // [mt][nt]
#pragma unroll
    for (int mt = 0; mt < 2; ++mt)
#pragma unroll
        for (int nt = 0; nt < 2; ++nt)
#pragma unroll
            for (int r = 0; r < 16; ++r) acc[mt][nt][r] = 0.f;

    GlobRegs g[3];                 // rotating 3-deep prefetch slots

    auto load_g = [&](int kt, GlobRegs& s) {
#pragma unroll
        for (int q = 0; q < 2; ++q) {
#pragma unroll
            for (int mt = 0; mt < 2; ++mt)
                s.a[mt][q] = wexp[(size_t)(((kt * 2 + q) * 2 + mt) * 64 + lw)];
            int pb = kt * 16 + q * 8 + kh * 4;
#pragma unroll
            for (int j = 0; j < 4; ++j)
                s.tv[q * 4 + j] = tc[(size_t)(pb + j) * 32];
        }
    };

    auto compute_step = [&](int kt, const GlobRegs& s) {
#pragma unroll
        for (int q = 0; q < 2; ++q) {
            int bi = kt * 8 + q * 4 + kh * 2;
            float4 c0 = B0f4[bi], c1 = B0f4[bi + 1];
            float4 d0 = B1f4[bi], d1 = B1f4[bi + 1];
            float2 bb[4] = {make_float2(c0.x, c0.y), make_float2(c0.z, c0.w),
                            make_float2(c1.x, c1.y), make_float2(c1.z, c1.w)};
            float2 dd[4] = {make_float2(d0.x, d0.y), make_float2(d0.z, d0.w),
                            make_float2(d1.x, d1.y), make_float2(d1.z, d1.w)};
            uint32_t f0[4], f1[4];
#pragma unroll
            for (int j = 0; j < 4; ++j) {
                float2 tvv = s.tv[q * 4 + j];
                f0[j] = packbf(cmul_pk(bb[j], tvv));
                f1[j] = packbf(cmul_pk(dd[j], tvv));
            }
            union { uint4 u; bf16x8 v; } F0, F1, A0, A1;
            F0.u = make_uint4(f0[0], f0[1], f0[2], f0[3]);
            F1.u = make_uint4(f1[0], f1[1], f1[2], f1[3]);
            A0.u = s.a[0][q];
            A1.u = s.a[1][q];
            acc[0][0] = __builtin_amdgcn_mfma_f32_32x32x16_bf16(A0.v, F0.v, acc[0][0], 0, 0, 0);
            acc[1][0] = __builtin_amdgcn_mfma_f32_32x32x16_bf16(A1.v, F0.v, acc[1][0], 0, 0, 0);
            acc[0][1] = __builtin_amdgcn_mfma_f32_32x32x16_bf16(A0.v, F1.v, acc[0][1], 0, 0, 0);
            acc[1][1] = __builtin_amdgcn_mfma_f32_32x32x16_bf16(A1.v, F1.v, acc[1][1], 0, 0, 0);
        }
    };

    load_g(kt0 + 0, g[0]);
    load_g(kt0 + 1, g[1]);
    load_g(kt0 + 2, g[2]);
#pragma unroll
    for (int i = 0; i < KTW; ++i) {          // fully unrolled: i%3 is static
        compute_step(kt0 + i, g[i % 3]);
        if (i + 3 < KTW) load_g(kt0 + i + 3, g[i % 3]);
    }

    // ---- cross-wave reduction: 2 rounds (nt), both m-tiles per round ----
    __syncthreads();                   // Base dead, reuse as Red
    float* Red = ldsp;                 // 8 waves x 2 mt x 1024 floats = 64 KB
    // C/D layout (m74): col = lane&31, row = (r&3) + 8*(r>>2) + 4*(lane>>5)
#pragma unroll
    for (int nt = 0; nt < 2; ++nt) {
#pragma unroll
        for (int mt = 0; mt < 2; ++mt)
#pragma unroll
            for (int r = 0; r < 16; ++r)
                Red[(w * 2 + mt) * 1024 + r * 64 + lw] = acc[mt][nt][r];
        __syncthreads();
#pragma unroll
        for (int ri = 0; ri < 2; ++ri) {
            int tau = t + ri * 512;            // task id in [0, 1024)
            int mtr = tau >> 9;                // m-tile this task reduces
            int s = tau & 511;
            int row = s >> 4;                  // 0..31
            int colb = (s & 15) * 2;           // even column
            int rr = (row & 3) | ((row >> 3) << 2);
            int lane0 = colb + ((row >> 2) & 1) * 32;
            float sx = 0.f, sy = 0.f;
#pragma unroll
            for (int ww = 0; ww < 8; ++ww) {
                int base = (ww * 2 + mtr) * 1024 + rr * 64 + lane0;
                sx += Red[base];
                sy += Red[base + 1];
            }
            *(float2*)(out + (size_t)(mtr * 32 + row) * L + (size_t)bn * BN
                       + nt * 32 + colb) = make_float2(sx, sy);
        }
        __syncthreads();
    }
}

// ---------------------------------------------------------------------------
extern "C" void kernel_launch(void* const* d_in, const int* in_sizes, int n_in,
                              void* d_out, int out_size, void* d_ws, size_t ws_size,
                              hipStream_t stream) {
    const float* Ain = nullptr;
    const float* Win = nullptr;
    for (int i = 0; i < n_in; ++i) {
        if (in_sizes[i] == 2 * P) Ain = (const float*)d_in[i];
        else if (in_sizes[i] == 2 * HN * P) Win = (const float*)d_in[i];
    }
    if (!Ain) Ain = (const float*)d_in[0];
    if (!Win) Win = (const float*)d_in[1];
    (void)out_size; (void)ws_size;
    uint4* wexp = (uint4*)d_ws;                                  // 512 KB
    float2* tcol = (float2*)((char*)d_ws + 512 * 1024);          // +512 KB
    float2* a32 = (float2*)((char*)d_ws + 1024 * 1024);          // +16 KB
    float2* abase = (float2*)((char*)d_ws + 2 * 1024 * 1024);    // +4 MB
    mv_prep<<<128, 256, 0, stream>>>(Win, Ain, wexp, tcol, a32, abase);
    mv_main<<<256, 512, 0, stream>>>(wexp, tcol, a32, abase, (float*)d_out);
}